// Round 5
// baseline (412.354 us; speedup 1.0000x reference)
//
#include <hip/hip_runtime.h>
#include <math.h>

#define DIMN 1024
#define NH 16
#define HD 64
#define BATCH 2
#define SEQ 2048
#define MROWS (BATCH*SEQ)   // 4096
#define NKB   (DIMN/32)     // 32 k-blocks

typedef unsigned short u16;
typedef unsigned int u32;
typedef __attribute__((ext_vector_type(8))) short bf16x8;  // 8 bf16 = 4 VGPR
typedef __attribute__((ext_vector_type(4))) float f32x4;

__device__ __forceinline__ u16 f2bf(float f) {             // RNE float->bf16 (bits)
    unsigned u = __float_as_uint(f);
    u += 0x7FFF + ((u >> 16) & 1);
    return (u16)(u >> 16);
}
__device__ __forceinline__ float bf2f(u16 s) {
    return __uint_as_float(((unsigned)s) << 16);
}

#define GLOADLDS16(g, s)                                                     \
    __builtin_amdgcn_global_load_lds(                                        \
        (const __attribute__((address_space(1))) void*)(g),                  \
        (__attribute__((address_space(3))) void*)(s), 16, 0, 0)

// ------- pack fp32 [R][1024] -> fragment-major bf16 hi/lo -------
// granule g = (rb*NKB + kb)*64 + lane ; lane = fq*16+fr holds
// src[rb*16+fr][kb*32 + fq*8 .. +8] as 8 u16 at dst[g*8].
__global__ __launch_bounds__(256)
void pack_hilo(const float* __restrict__ src, u16* __restrict__ dh,
               u16* __restrict__ dl, int ngran)
{
    int g = blockIdx.x * 256 + threadIdx.x;
    if (g >= ngran) return;
    const int lane = g & 63;
    const int kb   = (g >> 6) & (NKB - 1);
    const int rb   = g >> 11;
    const int row  = rb * 16 + (lane & 15);
    const int col  = kb * 32 + (lane >> 4) * 8;
    const float* s = src + (size_t)row * DIMN + col;
    float4 v0 = *(const float4*)s;
    float4 v1 = *(const float4*)(s + 4);
    ushort4 h0, h1, l0, l1;
    h0.x = f2bf(v0.x); l0.x = f2bf(v0.x - bf2f(h0.x));
    h0.y = f2bf(v0.y); l0.y = f2bf(v0.y - bf2f(h0.y));
    h0.z = f2bf(v0.z); l0.z = f2bf(v0.z - bf2f(h0.z));
    h0.w = f2bf(v0.w); l0.w = f2bf(v0.w - bf2f(h0.w));
    h1.x = f2bf(v1.x); l1.x = f2bf(v1.x - bf2f(h1.x));
    h1.y = f2bf(v1.y); l1.y = f2bf(v1.y - bf2f(h1.y));
    h1.z = f2bf(v1.z); l1.z = f2bf(v1.z - bf2f(h1.z));
    h1.w = f2bf(v1.w); l1.w = f2bf(v1.w - bf2f(h1.w));
    *(ushort4*)(dh + (size_t)g * 8)     = h0;
    *(ushort4*)(dh + (size_t)g * 8 + 4) = h1;
    *(ushort4*)(dl + (size_t)g * 8)     = l0;
    *(ushort4*)(dl + (size_t)g * 8 + 4) = l1;
}

// ------- fragment-packed MFMA GEMM: zero LDS, zero barriers -------
// Wave tile = MF*16 x NF*16; block = 4 waves (2x2). Every fragment is one
// coalesced 1KB global_load_dwordx4 from the packed layout (L2-resident W).
// 3 MFMA per frag pair: hi*hi + hi*lo + lo*hi (fp32-grade).
template<int MF, int NF, bool QKV>
__global__ __launch_bounds__(256)
void pgemm(const u16* __restrict__ Aph, const u16* __restrict__ Apl,
           const u16* __restrict__ Wph0, const u16* __restrict__ Wpl0,
           const u16* __restrict__ Wph1, const u16* __restrict__ Wpl1,
           const u16* __restrict__ Wph2, const u16* __restrict__ Wpl2,
           const float* __restrict__ b0, const float* __restrict__ b1,
           const float* __restrict__ b2,
           u16* __restrict__ Qh, u16* __restrict__ Ql,
           u16* __restrict__ Kh, u16* __restrict__ Kl,
           float* __restrict__ Vw, float* __restrict__ Yout)
{
    const u16* Wph = Wph0; const u16* Wpl = Wpl0; const float* bias = b0;
    if (QKV) {
        if (blockIdx.z == 1)      { Wph = Wph1; Wpl = Wpl1; bias = b1; }
        else if (blockIdx.z == 2) { Wph = Wph2; Wpl = Wpl2; bias = b2; }
    }

    const int tid  = threadIdx.x;
    const int lane = tid & 63;
    const int wid  = tid >> 6;
    const int wr   = wid >> 1;
    const int wc   = wid & 1;
    const int mb0  = blockIdx.y * (2*MF) + wr*MF;   // 16-row block index
    const int nb0  = blockIdx.x * (2*NF) + wc*NF;

    // packed elem offset: blk*NKB*512 + kb*512 + lane*8
    const u16* Ah = Aph + (size_t)mb0 * (NKB*512) + lane*8;
    const u16* Al = Apl + (size_t)mb0 * (NKB*512) + lane*8;
    const u16* Bh = Wph + (size_t)nb0 * (NKB*512) + lane*8;
    const u16* Bl = Wpl + (size_t)nb0 * (NKB*512) + lane*8;

    f32x4 acc[MF][NF];
    #pragma unroll
    for (int m = 0; m < MF; ++m)
        #pragma unroll
        for (int n = 0; n < NF; ++n)
            acc[m][n] = (f32x4){0.f, 0.f, 0.f, 0.f};

    for (int kb = 0; kb < NKB; ++kb) {
        const int ko = kb * 512;
        bf16x8 ah[MF], al[MF], bh[NF], bl[NF];
        #pragma unroll
        for (int m = 0; m < MF; ++m) {
            ah[m] = *(const bf16x8*)(Ah + ko + m*(NKB*512));
            al[m] = *(const bf16x8*)(Al + ko + m*(NKB*512));
        }
        #pragma unroll
        for (int n = 0; n < NF; ++n) {
            bh[n] = *(const bf16x8*)(Bh + ko + n*(NKB*512));
            bl[n] = *(const bf16x8*)(Bl + ko + n*(NKB*512));
        }
        #pragma unroll
        for (int m = 0; m < MF; ++m)
            #pragma unroll
            for (int n = 0; n < NF; ++n) {
                acc[m][n] = __builtin_amdgcn_mfma_f32_16x16x32_bf16(ah[m], bh[n], acc[m][n], 0, 0, 0);
                acc[m][n] = __builtin_amdgcn_mfma_f32_16x16x32_bf16(ah[m], bl[n], acc[m][n], 0, 0, 0);
                acc[m][n] = __builtin_amdgcn_mfma_f32_16x16x32_bf16(al[m], bh[n], acc[m][n], 0, 0, 0);
            }
    }

    // C/D map: col = lane&15, row = (lane>>4)*4 + j   [m89-verified]
    const int fr = lane & 15;
    const int fq = lane >> 4;
    #pragma unroll
    for (int n = 0; n < NF; ++n) {
        const int col = (nb0 + n)*16 + fr;
        const float bv = bias[col];
        #pragma unroll
        for (int m = 0; m < MF; ++m) {
            #pragma unroll
            for (int j = 0; j < 4; ++j) {
                const int row = (mb0 + m)*16 + fq*4 + j;
                float v = acc[m][n][j] + bv;
                if (QKV) {
                    const int b_ = row >> 11, t = row & (SEQ - 1);
                    const int hh = col >> 6, d = col & 63;
                    const size_t rb = (((size_t)b_*NH + hh)*SEQ + t)*HD;
                    if (blockIdx.z == 0) {            // Q: scaled, plain
                        v *= 0.03125f;
                        u16 hv = f2bf(v), lv = f2bf(v - bf2f(hv));
                        Qh[rb + d] = hv; Ql[rb + d] = lv;
                    } else if (blockIdx.z == 1) {     // K: d-swizzled for attn LDS
                        u16 hv = f2bf(v), lv = f2bf(v - bf2f(hv));
                        const int ds = d ^ ((t & 7) << 3);
                        Kh[rb + ds] = hv; Kl[rb + ds] = lv;
                    } else {                          // V: fp32 plain
                        Vw[rb + d] = v;
                    }
                } else {
                    Yout[(size_t)row*DIMN + col] = v;
                }
            }
        }
    }
}

// ---- V transpose + hi/lo + kc-slot swizzle: [B,H,T,64] -> [B,H,64,T] bf16 ----
__global__ __launch_bounds__(256)
void convV(const float* __restrict__ Vw, u16* __restrict__ Vth, u16* __restrict__ Vtl)
{
    __shared__ float Vs[64][68];
    const int tid = threadIdx.x;
    const int bh = blockIdx.y;
    const int t0 = blockIdx.x * 64;
    const float* src = Vw + ((size_t)bh*SEQ + t0)*HD;
    #pragma unroll
    for (int k = 0; k < 4; ++k) {
        int f4 = tid + k*256;
        int r = f4 >> 4, c4 = (f4 & 15) << 2;
        *(float4*)&Vs[r][c4] = *(const float4*)(src + (size_t)r*HD + c4);
    }
    __syncthreads();
    const int d  = tid >> 2;            // 0..63
    const int q2 = (tid & 3) << 4;      // base t: 0,16,32,48
    u16* oh = Vth + ((size_t)bh*HD + d)*SEQ + t0;
    u16* ol = Vtl + ((size_t)bh*HD + d)*SEQ + t0;
    #pragma unroll
    for (int p = 0; p < 4; ++p) {
        const int lt = q2 + p*4;                      // linear t, run of 4
        const int t_sw = (lt & 32) | ((((lt >> 3) & 3) ^ (d & 3)) << 3) | (lt & 7);
        ushort4 hv, lv; float v;
        v = Vs[lt + 0][d]; hv.x = f2bf(v); lv.x = f2bf(v - bf2f(hv.x));
        v = Vs[lt + 1][d]; hv.y = f2bf(v); lv.y = f2bf(v - bf2f(hv.y));
        v = Vs[lt + 2][d]; hv.z = f2bf(v); lv.z = f2bf(v - bf2f(hv.z));
        v = Vs[lt + 3][d]; hv.w = f2bf(v); lv.w = f2bf(v - bf2f(hv.w));
        *(ushort4*)(oh + t_sw) = hv;
        *(ushort4*)(ol + t_sw) = lv;
    }
}

// ---------------- MFMA flash attention (pair-balanced, swapped QK^T) --------
__global__ __launch_bounds__(256)
void attn_mfma(const u16* __restrict__ Qhg, const u16* __restrict__ Qlg,
               const u16* __restrict__ Khg, const u16* __restrict__ Klg,
               const u16* __restrict__ Vthg, const u16* __restrict__ Vtlg,
               float* __restrict__ Oc)
{
    __shared__ u16 KVS[2][4][2048];   // [buf][Kh,Kl,Vth,Vtl][tile] 32 KB
    __shared__ u16 PhS[4][640];       // per-wave P hi [16q][stride 40]
    __shared__ u16 PlS[4][640];

    const int tid  = threadIdx.x;
    const int lane = tid & 63;
    const int w    = tid >> 6;
    const int fr   = lane & 15;
    const int fq   = lane >> 4;
    const int bh   = blockIdx.y;
    const int b_   = bh >> 4;
    const int h    = bh & 15;

    auto stage = [&](int buf, int kt2) {
        u16* dst = &KVS[buf][w][0];
        if (w < 2) {
            const u16* g = (w == 0 ? Khg : Klg) +
                ((size_t)bh*SEQ + (size_t)kt2*32 + (lane>>3))*HD + ((lane&7)<<3);
            #pragma unroll
            for (int i = 0; i < 4; ++i)
                GLOADLDS16(g + (size_t)i*8*HD, dst + i*512);
        } else {
            const u16* g = (w == 2 ? Vthg : Vtlg) +
                ((size_t)bh*HD + (lane>>2))*SEQ + (size_t)kt2*32 + ((lane&3)<<3);
            #pragma unroll
            for (int i = 0; i < 4; ++i)
                GLOADLDS16(g + (size_t)i*16*SEQ, dst + i*512);
        }
    };

    #pragma unroll 1
    for (int pass = 0; pass < 2; ++pass) {
        const int qt   = pass ? (31 - blockIdx.x) : blockIdx.x;
        const int qabs = qt*64 + w*16 + fr;
        const int nt   = 2*qt + 2;

        bf16x8 qh[2], ql[2];
        {
            const size_t qrow = ((size_t)bh*SEQ + qabs)*HD;
            #pragma unroll
            for (int ks = 0; ks < 2; ++ks) {
                qh[ks] = *(const bf16x8*)&Qhg[qrow + ks*32 + (fq<<3)];
                ql[ks] = *(const bf16x8*)&Qlg[qrow + ks*32 + (fq<<3)];
            }
        }

        f32x4 o[4];
        #pragma unroll
        for (int md = 0; md < 4; ++md) o[md] = (f32x4){0.f,0.f,0.f,0.f};
        float mrun = -INFINITY, lrun = 0.f;

        __syncthreads();               // prior pass's LDS reads complete
        stage(0, 0);
        int cur = 0;

        for (int kt = 0; kt < nt; ++kt) {
            __syncthreads();                       // staged tile landed
            if (kt + 1 < nt) stage(cur ^ 1, kt + 1);

            f32x4 s0 = (f32x4){0.f,0.f,0.f,0.f};
            f32x4 s1 = (f32x4){0.f,0.f,0.f,0.f};
            #pragma unroll
            for (int ks = 0; ks < 2; ++ks) {
                const int sl = (((ks*4 + fq) ^ (fr & 7)) << 3);   // swizzled d-slot
                bf16x8 a0h = *(const bf16x8*)&KVS[cur][0][fr*64 + sl];
                bf16x8 a0l = *(const bf16x8*)&KVS[cur][1][fr*64 + sl];
                bf16x8 a1h = *(const bf16x8*)&KVS[cur][0][(16+fr)*64 + sl];
                bf16x8 a1l = *(const bf16x8*)&KVS[cur][1][(16+fr)*64 + sl];
                s0 = __builtin_amdgcn_mfma_f32_16x16x32_bf16(a0h, qh[ks], s0, 0,0,0);
                s0 = __builtin_amdgcn_mfma_f32_16x16x32_bf16(a0h, ql[ks], s0, 0,0,0);
                s0 = __builtin_amdgcn_mfma_f32_16x16x32_bf16(a0l, qh[ks], s0, 0,0,0);
                s1 = __builtin_amdgcn_mfma_f32_16x16x32_bf16(a1h, qh[ks], s1, 0,0,0);
                s1 = __builtin_amdgcn_mfma_f32_16x16x32_bf16(a1h, ql[ks], s1, 0,0,0);
                s1 = __builtin_amdgcn_mfma_f32_16x16x32_bf16(a1l, qh[ks], s1, 0,0,0);
            }

            const int kb = kt*32 + fq*4;
            #pragma unroll
            for (int j = 0; j < 4; ++j) {
                if (kb + j      > qabs) s0[j] = -INFINITY;
                if (kb + 16 + j > qabs) s1[j] = -INFINITY;
            }

            float pm = fmaxf(fmaxf(fmaxf(s0[0],s0[1]), fmaxf(s0[2],s0[3])),
                             fmaxf(fmaxf(s1[0],s1[1]), fmaxf(s1[2],s1[3])));
            pm = fmaxf(pm, __shfl_xor(pm, 16));
            pm = fmaxf(pm, __shfl_xor(pm, 32));
            const float mnew = fmaxf(mrun, pm);
            const float fac  = __expf(mrun - mnew);
            float p[8];
            #pragma unroll
            for (int j = 0; j < 4; ++j) {
                p[j]   = __expf(s0[j] - mnew);
                p[4+j] = __expf(s1[j] - mnew);
            }
            float ls = ((p[0]+p[1]) + (p[2]+p[3])) + ((p[4]+p[5]) + (p[6]+p[7]));
            ls += __shfl_xor(ls, 16);
            ls += __shfl_xor(ls, 32);
            lrun = lrun * fac + ls;
            mrun = mnew;
            #pragma unroll
            for (int md = 0; md < 4; ++md) {
                o[md][0] *= fac; o[md][1] *= fac; o[md][2] *= fac; o[md][3] *= fac;
            }

            u16 ph[8], pl[8];
            #pragma unroll
            for (int i = 0; i < 8; ++i) {
                ph[i] = f2bf(p[i]);
                pl[i] = f2bf(p[i] - bf2f(ph[i]));
            }
            {
                const int pb = fr*40 + fq*4;
                uint2 w0, w1;
                w0.x = (u32)ph[0] | ((u32)ph[1] << 16);
                w0.y = (u32)ph[2] | ((u32)ph[3] << 16);
                w1.x = (u32)ph[4] | ((u32)ph[5] << 16);
                w1.y = (u32)ph[6] | ((u32)ph[7] << 16);
                *(uint2*)&PhS[w][pb]      = w0;
                *(uint2*)&PhS[w][pb + 16] = w1;
                w0.x = (u32)pl[0] | ((u32)pl[1] << 16);
                w0.y = (u32)pl[2] | ((u32)pl[3] << 16);
                w1.x = (u32)pl[4] | ((u32)pl[5] << 16);
                w1.y = (u32)pl[6] | ((u32)pl[7] << 16);
                *(uint2*)&PlS[w][pb]      = w0;
                *(uint2*)&PlS[w][pb + 16] = w1;
            }

            bf16x8 bph = *(const bf16x8*)&PhS[w][fr*40 + (fq<<3)];
            bf16x8 bpl = *(const bf16x8*)&PlS[w][fr*40 + (fq<<3)];
            #pragma unroll
            for (int md = 0; md < 4; ++md) {
                const int vsl = ((fq ^ (fr & 3)) << 3);
                bf16x8 avh = *(const bf16x8*)&KVS[cur][2][(md*16+fr)*32 + vsl];
                bf16x8 avl = *(const bf16x8*)&KVS[cur][3][(md*16+fr)*32 + vsl];
                o[md] = __builtin_amdgcn_mfma_f32_16x16x32_bf16(avh, bph, o[md], 0,0,0);
                o[md] = __builtin_amdgcn_mfma_f32_16x16x32_bf16(avh, bpl, o[md], 0,0,0);
                o[md] = __builtin_amdgcn_mfma_f32_16x16x32_bf16(avl, bph, o[md], 0,0,0);
            }
            cur ^= 1;
        }

        // epilogue: fp32 context, 4-contig d per (md) -> float4
        const float inv = 1.f / lrun;
        float* dst = Oc + ((size_t)b_*SEQ + qabs)*DIMN + h*64;
        #pragma unroll
        for (int md = 0; md < 4; ++md) {
            float4 v;
            v.x = o[md][0]*inv; v.y = o[md][1]*inv;
            v.z = o[md][2]*inv; v.w = o[md][3]*inv;
            *(float4*)(dst + md*16 + fq*4) = v;
        }
    }
}

extern "C" void kernel_launch(void* const* d_in, const int* in_sizes, int n_in,
                              void* d_out, int out_size, void* d_ws, size_t ws_size,
                              hipStream_t stream)
{
    const float* x  = (const float*)d_in[0];
    const float* Wq = (const float*)d_in[1];
    const float* bq = (const float*)d_in[2];
    const float* Wk = (const float*)d_in[3];
    const float* bk = (const float*)d_in[4];
    const float* Wv = (const float*)d_in[5];
    const float* bv = (const float*)d_in[6];
    const float* Wo = (const float*)d_in[7];
    const float* bo = (const float*)d_in[8];
    float* out = (float*)d_out;

    const size_t NX = (size_t)MROWS * DIMN;   // 4 Mi elems
    const size_t NW = (size_t)DIMN * DIMN;    // 1 Mi elems

    // 96 MB workspace
    u16* Xph = (u16*)d_ws;        // packed x hi (also reused for packed ctx)
    u16* Xpl = Xph + NX;
    u16* WpQh = Xpl + NX;  u16* WpQl = WpQh + NW;
    u16* WpKh = WpQl + NW; u16* WpKl = WpKh + NW;
    u16* WpVh = WpKl + NW; u16* WpVl = WpVh + NW;
    u16* WpOh = WpVl + NW; u16* WpOl = WpOh + NW;
    u16* Qh  = WpOl + NW;
    u16* Ql  = Qh + NX;
    u16* Kh  = Ql + NX;
    u16* Kl  = Kh + NX;
    u16* Vth = Kl + NX;
    u16* Vtl = Vth + NX;
    float* Vw = (float*)(Vtl + NX);           // NX fp32; reused as attn ctx Oc

    const int ngx = (int)(NX / 8);            // granules for R=4096
    const int ngw = (int)(NW / 8);            // granules for R=1024
    pack_hilo<<<ngx/256, 256, 0, stream>>>(x,  Xph, Xpl, ngx);
    pack_hilo<<<ngw/256, 256, 0, stream>>>(Wq, WpQh, WpQl, ngw);
    pack_hilo<<<ngw/256, 256, 0, stream>>>(Wk, WpKh, WpKl, ngw);
    pack_hilo<<<ngw/256, 256, 0, stream>>>(Wv, WpVh, WpVl, ngw);
    pack_hilo<<<ngw/256, 256, 0, stream>>>(Wo, WpOh, WpOl, ngw);

    // QKV: block 128x128 (MF=4,NF=4), grid 8x32x3 = 768 blocks
    dim3 gq(DIMN/128, MROWS/128, 3);
    pgemm<4,4,true><<<gq, 256, 0, stream>>>(Xph, Xpl,
        WpQh, WpQl, WpKh, WpKl, WpVh, WpVl, bq, bk, bv,
        Qh, Ql, Kh, Kl, Vw, nullptr);

    dim3 gv(SEQ / 64, BATCH * NH);
    convV<<<gv, 256, 0, stream>>>(Vw, Vth, Vtl);

    float* Oc = Vw;                           // reuse (Vw dead after convV)
    dim3 ga(16, BATCH * NH);                  // pair-balanced: 68 tiles/block
    attn_mfma<<<ga, 256, 0, stream>>>(Qh, Ql, Kh, Kl, Vth, Vtl, Oc);

    // pack ctx into Xp (x-pack dead after QKV gemm)
    pack_hilo<<<ngx/256, 256, 0, stream>>>(Oc, Xph, Xpl, ngx);

    // out-proj: block 128x64 (MF=4,NF=2), grid 16x32 = 512 blocks
    dim3 gp(DIMN/64, MROWS/128, 1);
    pgemm<4,2,false><<<gp, 256, 0, stream>>>(Xph, Xpl,
        WpOh, WpOl, nullptr, nullptr, nullptr, nullptr, bo, nullptr, nullptr,
        nullptr, nullptr, nullptr, nullptr, nullptr, out);
}

// Round 6
// 339.167 us; speedup vs baseline: 1.2158x; 1.2158x over previous
//
#include <hip/hip_runtime.h>
#include <math.h>

#define DIMN 1024
#define NH 16
#define HD 64
#define BATCH 2
#define SEQ 2048
#define MROWS (BATCH*SEQ)   // 4096

typedef unsigned short u16;
typedef unsigned int u32;
typedef __attribute__((ext_vector_type(8))) short bf16x8;  // 8 bf16 = 4 VGPR
typedef __attribute__((ext_vector_type(4))) float f32x4;

__device__ __forceinline__ u16 f2bf(float f) {             // RNE float->bf16 (bits)
    unsigned u = __float_as_uint(f);
    u += 0x7FFF + ((u >> 16) & 1);
    return (u16)(u >> 16);
}
__device__ __forceinline__ float bf2f(u16 s) {
    return __uint_as_float(((unsigned)s) << 16);
}

#define GLOADLDS16(g, s)                                                     \
    __builtin_amdgcn_global_load_lds(                                        \
        (const __attribute__((address_space(1))) void*)(g),                  \
        (__attribute__((address_space(3))) void*)(s), 16, 0, 0)

// ---------------- hi/lo split: fp32 -> bf16 hi + bf16 lo ----------------
__global__ __launch_bounds__(256)
void split_hilo(const float* __restrict__ src, u16* __restrict__ h,
                u16* __restrict__ l, int n4)
{
    int i = blockIdx.x * 256 + threadIdx.x;
    if (i >= n4) return;
    float4 v = ((const float4*)src)[i];
    ushort4 hv, lv;
    hv.x = f2bf(v.x); lv.x = f2bf(v.x - bf2f(hv.x));
    hv.y = f2bf(v.y); lv.y = f2bf(v.y - bf2f(hv.y));
    hv.z = f2bf(v.z); lv.z = f2bf(v.z - bf2f(hv.z));
    hv.w = f2bf(v.w); lv.w = f2bf(v.w - bf2f(hv.w));
    ((ushort4*)h)[i] = hv;
    ((ushort4*)l)[i] = lv;
}

// one launch for all four weight matrices (z selects)
__global__ __launch_bounds__(256)
void split4_hilo(const float* __restrict__ s0, const float* __restrict__ s1,
                 const float* __restrict__ s2, const float* __restrict__ s3,
                 u16* __restrict__ h0, u16* __restrict__ l0,
                 u16* __restrict__ h1, u16* __restrict__ l1,
                 u16* __restrict__ h2, u16* __restrict__ l2,
                 u16* __restrict__ h3, u16* __restrict__ l3, int n4)
{
    const float* src; u16* h; u16* l;
    switch (blockIdx.z) {
        case 0: src = s0; h = h0; l = l0; break;
        case 1: src = s1; h = h1; l = l1; break;
        case 2: src = s2; h = h2; l = l2; break;
        default: src = s3; h = h3; l = l3; break;
    }
    int i = blockIdx.x * 256 + threadIdx.x;
    if (i >= n4) return;
    float4 v = ((const float4*)src)[i];
    ushort4 hv, lv;
    hv.x = f2bf(v.x); lv.x = f2bf(v.x - bf2f(hv.x));
    hv.y = f2bf(v.y); lv.y = f2bf(v.y - bf2f(hv.y));
    hv.z = f2bf(v.z); lv.z = f2bf(v.z - bf2f(hv.z));
    hv.w = f2bf(v.w); lv.w = f2bf(v.w - bf2f(hv.w));
    ((ushort4*)h)[i] = hv;
    ((ushort4*)l)[i] = lv;
}

// ---------------- split-bf16 MFMA GEMM: Y = A @ W^T + bias ----------------
// BM=128 rows, BN = NF*32 cols, BK=32. 4 waves (2x2); wave tile 64 x NF*16.
// blockIdx.x = ROW block (fastest-varying -> same-XCD blocks share W panel,
// and each XCD touches only 4 A panels: L2-resident working set ~2.5 MB).
template<int NF, bool QKV>
__global__ __launch_bounds__(256)
void mfma_gemm(const u16* __restrict__ Ah, const u16* __restrict__ Al,
               const u16* __restrict__ Wh0, const u16* __restrict__ Wl0,
               const u16* __restrict__ Wh1, const u16* __restrict__ Wl1,
               const u16* __restrict__ Wh2, const u16* __restrict__ Wl2,
               const float* __restrict__ b0, const float* __restrict__ b1,
               const float* __restrict__ b2,
               u16* __restrict__ Qh, u16* __restrict__ Ql,
               u16* __restrict__ Kh, u16* __restrict__ Kl,
               float* __restrict__ Vw, float* __restrict__ Yout)
{
    constexpr int BM = 128;
    constexpr int BN = NF * 32;
    constexpr int BK = 32;
    __shared__ u16 AhS[BM*BK], AlS[BM*BK], WhS[BN*BK], WlS[BN*BK];

    const u16* Wh = Wh0; const u16* Wl = Wl0; const float* bias = b0;
    if (QKV) {
        if (blockIdx.z == 1)      { Wh = Wh1; Wl = Wl1; bias = b1; }
        else if (blockIdx.z == 2) { Wh = Wh2; Wl = Wl2; bias = b2; }
    }

    const int tid  = threadIdx.x;
    const int lane = tid & 63;
    const int wid  = tid >> 6;
    const int wr   = wid >> 1;
    const int wc   = wid & 1;

    const int m0 = blockIdx.x * BM;     // row block (x fastest)
    const int n0 = blockIdx.y * BN;

    const int srow = lane >> 2;
    const int skc  = (lane & 3) << 3;
    const int c0 = wid * 2, c1 = wid * 2 + 1;
    const size_t aoffg0 = (size_t)(m0 + c0*16 + srow) * DIMN + skc;
    const size_t aoffg1 = (size_t)(m0 + c1*16 + srow) * DIMN + skc;
    const size_t woffg0 = (size_t)(n0 + c0*16 + srow) * DIMN + skc;
    const size_t woffg1 = (size_t)(n0 + c1*16 + srow) * DIMN + skc;
    const bool doW = (c0 < BN/16);      // NF=2: only waves 0,1 stage W

    f32x4 acc[4][NF];
    #pragma unroll
    for (int m = 0; m < 4; ++m)
        #pragma unroll
        for (int n = 0; n < NF; ++n)
            acc[m][n] = (f32x4){0.f, 0.f, 0.f, 0.f};

    const int fr = lane & 15;
    const int fq = lane >> 4;
    const int aoff = (wr*64 + fr) * BK + fq*8;
    const int boff = (wc*(NF*16) + fr) * BK + fq*8;

    for (int k0 = 0; k0 < DIMN; k0 += BK) {
        GLOADLDS16(Ah + aoffg0 + k0, &AhS[c0*512]);
        GLOADLDS16(Ah + aoffg1 + k0, &AhS[c1*512]);
        GLOADLDS16(Al + aoffg0 + k0, &AlS[c0*512]);
        GLOADLDS16(Al + aoffg1 + k0, &AlS[c1*512]);
        if (doW) {
            GLOADLDS16(Wh + woffg0 + k0, &WhS[c0*512]);
            GLOADLDS16(Wh + woffg1 + k0, &WhS[c1*512]);
            GLOADLDS16(Wl + woffg0 + k0, &WlS[c0*512]);
            GLOADLDS16(Wl + woffg1 + k0, &WlS[c1*512]);
        }
        __syncthreads();

        bf16x8 ah[4], al[4], bh[NF], bl[NF];
        #pragma unroll
        for (int m = 0; m < 4; ++m) {
            ah[m] = *(const bf16x8*)&AhS[aoff + m*16*BK];
            al[m] = *(const bf16x8*)&AlS[aoff + m*16*BK];
        }
        #pragma unroll
        for (int n = 0; n < NF; ++n) {
            bh[n] = *(const bf16x8*)&WhS[boff + n*16*BK];
            bl[n] = *(const bf16x8*)&WlS[boff + n*16*BK];
        }
        #pragma unroll
        for (int m = 0; m < 4; ++m)
            #pragma unroll
            for (int n = 0; n < NF; ++n) {
                acc[m][n] = __builtin_amdgcn_mfma_f32_16x16x32_bf16(ah[m], bh[n], acc[m][n], 0, 0, 0);
                acc[m][n] = __builtin_amdgcn_mfma_f32_16x16x32_bf16(ah[m], bl[n], acc[m][n], 0, 0, 0);
                acc[m][n] = __builtin_amdgcn_mfma_f32_16x16x32_bf16(al[m], bh[n], acc[m][n], 0, 0, 0);
            }
        __syncthreads();
    }

    // C/D map: col = lane&15, row = (lane>>4)*4 + j   [m89-verified]
    #pragma unroll
    for (int n = 0; n < NF; ++n) {
        const int col = n0 + wc*(NF*16) + n*16 + fr;
        const float bv = bias[col];
        #pragma unroll
        for (int m = 0; m < 4; ++m) {
            #pragma unroll
            for (int j = 0; j < 4; ++j) {
                const int row = m0 + wr*64 + m*16 + fq*4 + j;
                float v = acc[m][n][j] + bv;
                if (QKV) {
                    const int b_ = row >> 11, t = row & (SEQ - 1);
                    const int hh = col >> 6, d = col & 63;
                    const size_t rb = (((size_t)b_*NH + hh)*SEQ + t)*HD;
                    if (blockIdx.z == 0) {            // Q: scaled, plain
                        v *= 0.03125f;
                        u16 hv = f2bf(v), lv = f2bf(v - bf2f(hv));
                        Qh[rb + d] = hv; Ql[rb + d] = lv;
                    } else if (blockIdx.z == 1) {     // K: d-swizzled for attn LDS
                        u16 hv = f2bf(v), lv = f2bf(v - bf2f(hv));
                        const int ds = d ^ ((t & 7) << 3);
                        Kh[rb + ds] = hv; Kl[rb + ds] = lv;
                    } else {                          // V: fp32 plain
                        Vw[rb + d] = v;
                    }
                } else {
                    Yout[(size_t)row*DIMN + col] = v;
                }
            }
        }
    }
}

// ---- V transpose + hi/lo + kc-slot swizzle: [B,H,T,64] -> [B,H,64,T] bf16 ----
__global__ __launch_bounds__(256)
void convV(const float* __restrict__ Vw, u16* __restrict__ Vth, u16* __restrict__ Vtl)
{
    __shared__ float Vs[64][68];
    const int tid = threadIdx.x;
    const int bh = blockIdx.y;
    const int t0 = blockIdx.x * 64;
    const float* src = Vw + ((size_t)bh*SEQ + t0)*HD;
    #pragma unroll
    for (int k = 0; k < 4; ++k) {
        int f4 = tid + k*256;
        int r = f4 >> 4, c4 = (f4 & 15) << 2;
        *(float4*)&Vs[r][c4] = *(const float4*)(src + (size_t)r*HD + c4);
    }
    __syncthreads();
    const int d  = tid >> 2;            // 0..63
    const int q2 = (tid & 3) << 4;      // base t: 0,16,32,48
    u16* oh = Vth + ((size_t)bh*HD + d)*SEQ + t0;
    u16* ol = Vtl + ((size_t)bh*HD + d)*SEQ + t0;
    #pragma unroll
    for (int p = 0; p < 4; ++p) {
        const int lt = q2 + p*4;                      // linear t, run of 4
        const int t_sw = (lt & 32) | ((((lt >> 3) & 3) ^ (d & 3)) << 3) | (lt & 7);
        ushort4 hv, lv; float v;
        v = Vs[lt + 0][d]; hv.x = f2bf(v); lv.x = f2bf(v - bf2f(hv.x));
        v = Vs[lt + 1][d]; hv.y = f2bf(v); lv.y = f2bf(v - bf2f(hv.y));
        v = Vs[lt + 2][d]; hv.z = f2bf(v); lv.z = f2bf(v - bf2f(hv.z));
        v = Vs[lt + 3][d]; hv.w = f2bf(v); lv.w = f2bf(v - bf2f(hv.w));
        *(ushort4*)(oh + t_sw) = hv;
        *(ushort4*)(ol + t_sw) = lv;
    }
}

// ---------------- MFMA flash attention (pair-balanced, swapped QK^T) --------
// + T13 defer-max (skip O-rescale while tile max grows <= 8)
// + T5 setprio around MFMA clusters (attn blocks are independent: m191 +4-7%)
__global__ __launch_bounds__(256)
void attn_mfma(const u16* __restrict__ Qhg, const u16* __restrict__ Qlg,
               const u16* __restrict__ Khg, const u16* __restrict__ Klg,
               const u16* __restrict__ Vthg, const u16* __restrict__ Vtlg,
               u16* __restrict__ AH, u16* __restrict__ AL)
{
    __shared__ u16 KVS[2][4][2048];   // [buf][Kh,Kl,Vth,Vtl][tile] 32 KB
    __shared__ u16 PhS[4][640];       // per-wave P hi [16q][stride 40]
    __shared__ u16 PlS[4][640];

    const int tid  = threadIdx.x;
    const int lane = tid & 63;
    const int w    = tid >> 6;
    const int fr   = lane & 15;
    const int fq   = lane >> 4;
    const int bh   = blockIdx.y;
    const int b_   = bh >> 4;
    const int h    = bh & 15;

    auto stage = [&](int buf, int kt2) {
        u16* dst = &KVS[buf][w][0];
        if (w < 2) {
            const u16* g = (w == 0 ? Khg : Klg) +
                ((size_t)bh*SEQ + (size_t)kt2*32 + (lane>>3))*HD + ((lane&7)<<3);
            #pragma unroll
            for (int i = 0; i < 4; ++i)
                GLOADLDS16(g + (size_t)i*8*HD, dst + i*512);
        } else {
            const u16* g = (w == 2 ? Vthg : Vtlg) +
                ((size_t)bh*HD + (lane>>2))*SEQ + (size_t)kt2*32 + ((lane&3)<<3);
            #pragma unroll
            for (int i = 0; i < 4; ++i)
                GLOADLDS16(g + (size_t)i*16*SEQ, dst + i*512);
        }
    };

    #pragma unroll 1
    for (int pass = 0; pass < 2; ++pass) {
        const int qt   = pass ? (31 - blockIdx.x) : blockIdx.x;
        const int qabs = qt*64 + w*16 + fr;
        const int nt   = 2*qt + 2;

        bf16x8 qh[2], ql[2];
        {
            const size_t qrow = ((size_t)bh*SEQ + qabs)*HD;
            #pragma unroll
            for (int ks = 0; ks < 2; ++ks) {
                qh[ks] = *(const bf16x8*)&Qhg[qrow + ks*32 + (fq<<3)];
                ql[ks] = *(const bf16x8*)&Qlg[qrow + ks*32 + (fq<<3)];
            }
        }

        f32x4 o[4];
        #pragma unroll
        for (int md = 0; md < 4; ++md) o[md] = (f32x4){0.f,0.f,0.f,0.f};
        float mrun = -INFINITY, lrun = 0.f;

        __syncthreads();               // prior pass's LDS reads complete
        stage(0, 0);
        int cur = 0;

        for (int kt = 0; kt < nt; ++kt) {
            __syncthreads();                       // staged tile landed
            if (kt + 1 < nt) stage(cur ^ 1, kt + 1);

            f32x4 s0 = (f32x4){0.f,0.f,0.f,0.f};
            f32x4 s1 = (f32x4){0.f,0.f,0.f,0.f};
            __builtin_amdgcn_s_setprio(1);
            #pragma unroll
            for (int ks = 0; ks < 2; ++ks) {
                const int sl = (((ks*4 + fq) ^ (fr & 7)) << 3);   // swizzled d-slot
                bf16x8 a0h = *(const bf16x8*)&KVS[cur][0][fr*64 + sl];
                bf16x8 a0l = *(const bf16x8*)&KVS[cur][1][fr*64 + sl];
                bf16x8 a1h = *(const bf16x8*)&KVS[cur][0][(16+fr)*64 + sl];
                bf16x8 a1l = *(const bf16x8*)&KVS[cur][1][(16+fr)*64 + sl];
                s0 = __builtin_amdgcn_mfma_f32_16x16x32_bf16(a0h, qh[ks], s0, 0,0,0);
                s0 = __builtin_amdgcn_mfma_f32_16x16x32_bf16(a0h, ql[ks], s0, 0,0,0);
                s0 = __builtin_amdgcn_mfma_f32_16x16x32_bf16(a0l, qh[ks], s0, 0,0,0);
                s1 = __builtin_amdgcn_mfma_f32_16x16x32_bf16(a1h, qh[ks], s1, 0,0,0);
                s1 = __builtin_amdgcn_mfma_f32_16x16x32_bf16(a1h, ql[ks], s1, 0,0,0);
                s1 = __builtin_amdgcn_mfma_f32_16x16x32_bf16(a1l, qh[ks], s1, 0,0,0);
            }
            __builtin_amdgcn_s_setprio(0);

            const int kb = kt*32 + fq*4;
            #pragma unroll
            for (int j = 0; j < 4; ++j) {
                if (kb + j      > qabs) s0[j] = -INFINITY;
                if (kb + 16 + j > qabs) s1[j] = -INFINITY;
            }

            float pm = fmaxf(fmaxf(fmaxf(s0[0],s0[1]), fmaxf(s0[2],s0[3])),
                             fmaxf(fmaxf(s1[0],s1[1]), fmaxf(s1[2],s1[3])));
            pm = fmaxf(pm, __shfl_xor(pm, 16));
            pm = fmaxf(pm, __shfl_xor(pm, 32));

            // T13 defer-max: only rescale when the max actually grew > 8.
            if (!__all(pm - mrun <= 8.0f)) {
                const float mnew = fmaxf(mrun, pm);
                const float fac  = __expf(mrun - mnew);
                lrun *= fac;
                #pragma unroll
                for (int md = 0; md < 4; ++md) {
                    o[md][0] *= fac; o[md][1] *= fac;
                    o[md][2] *= fac; o[md][3] *= fac;
                }
                mrun = mnew;
            }
            float p[8];
            #pragma unroll
            for (int j = 0; j < 4; ++j) {
                p[j]   = __expf(s0[j] - mrun);
                p[4+j] = __expf(s1[j] - mrun);
            }
            float ls = ((p[0]+p[1]) + (p[2]+p[3])) + ((p[4]+p[5]) + (p[6]+p[7]));
            ls += __shfl_xor(ls, 16);
            ls += __shfl_xor(ls, 32);
            lrun += ls;

            u16 ph[8], pl[8];
            #pragma unroll
            for (int i = 0; i < 8; ++i) {
                ph[i] = f2bf(p[i]);
                pl[i] = f2bf(p[i] - bf2f(ph[i]));
            }
            {
                const int pb = fr*40 + fq*4;
                uint2 w0, w1;
                w0.x = (u32)ph[0] | ((u32)ph[1] << 16);
                w0.y = (u32)ph[2] | ((u32)ph[3] << 16);
                w1.x = (u32)ph[4] | ((u32)ph[5] << 16);
                w1.y = (u32)ph[6] | ((u32)ph[7] << 16);
                *(uint2*)&PhS[w][pb]      = w0;
                *(uint2*)&PhS[w][pb + 16] = w1;
                w0.x = (u32)pl[0] | ((u32)pl[1] << 16);
                w0.y = (u32)pl[2] | ((u32)pl[3] << 16);
                w1.x = (u32)pl[4] | ((u32)pl[5] << 16);
                w1.y = (u32)pl[6] | ((u32)pl[7] << 16);
                *(uint2*)&PlS[w][pb]      = w0;
                *(uint2*)&PlS[w][pb + 16] = w1;
            }

            bf16x8 bph = *(const bf16x8*)&PhS[w][fr*40 + (fq<<3)];
            bf16x8 bpl = *(const bf16x8*)&PlS[w][fr*40 + (fq<<3)];
            __builtin_amdgcn_s_setprio(1);
            #pragma unroll
            for (int md = 0; md < 4; ++md) {
                const int vsl = ((fq ^ (fr & 3)) << 3);
                bf16x8 avh = *(const bf16x8*)&KVS[cur][2][(md*16+fr)*32 + vsl];
                bf16x8 avl = *(const bf16x8*)&KVS[cur][3][(md*16+fr)*32 + vsl];
                o[md] = __builtin_amdgcn_mfma_f32_16x16x32_bf16(avh, bph, o[md], 0,0,0);
                o[md] = __builtin_amdgcn_mfma_f32_16x16x32_bf16(avh, bpl, o[md], 0,0,0);
                o[md] = __builtin_amdgcn_mfma_f32_16x16x32_bf16(avl, bph, o[md], 0,0,0);
            }
            __builtin_amdgcn_s_setprio(0);
            cur ^= 1;
        }

        // epilogue: hi/lo context in natural [B,T,DIMN] layout for the proj
        const float inv = 1.f / lrun;
        const size_t ob = ((size_t)b_*SEQ + qabs)*DIMN + h*64;
        #pragma unroll
        for (int md = 0; md < 4; ++md) {
            #pragma unroll
            for (int pr = 0; pr < 2; ++pr) {
                const int d0 = md*16 + fq*4 + pr*2;
                const float v0 = o[md][pr*2]   * inv;
                const float v1 = o[md][pr*2+1] * inv;
                u16 h0 = f2bf(v0), l0 = f2bf(v0 - bf2f(h0));
                u16 h1 = f2bf(v1), l1 = f2bf(v1 - bf2f(h1));
                *(u32*)&AH[ob + d0] = (u32)h0 | ((u32)h1 << 16);
                *(u32*)&AL[ob + d0] = (u32)l0 | ((u32)l1 << 16);
            }
        }
    }
}

extern "C" void kernel_launch(void* const* d_in, const int* in_sizes, int n_in,
                              void* d_out, int out_size, void* d_ws, size_t ws_size,
                              hipStream_t stream)
{
    const float* x  = (const float*)d_in[0];
    const float* Wq = (const float*)d_in[1];
    const float* bq = (const float*)d_in[2];
    const float* Wk = (const float*)d_in[3];
    const float* bk = (const float*)d_in[4];
    const float* Wv = (const float*)d_in[5];
    const float* bv = (const float*)d_in[6];
    const float* Wo = (const float*)d_in[7];
    const float* bo = (const float*)d_in[8];
    float* out = (float*)d_out;

    const size_t NX = (size_t)MROWS * DIMN;   // 4 Mi elems
    const size_t NW = (size_t)DIMN * DIMN;    // 1 Mi elems

    // 96 MB workspace
    u16* Xh  = (u16*)d_ws;
    u16* Xl  = Xh  + NX;
    u16* WhQ = Xl  + NX;  u16* WlQ = WhQ + NW;
    u16* WhK = WlQ + NW;  u16* WlK = WhK + NW;
    u16* WhV = WlK + NW;  u16* WlV = WhV + NW;
    u16* WhO = WlV + NW;  u16* WlO = WhO + NW;
    u16* Qh  = WlO + NW;
    u16* Ql  = Qh + NX;
    u16* Kh  = Ql + NX;
    u16* Kl  = Kh + NX;
    u16* Vth = Kl + NX;
    u16* Vtl = Vth + NX;
    float* Vw = (float*)(Vtl + NX);           // NX fp32
    u16* AH = Xh;                              // reuse (x-split dead after QKV)
    u16* AL = Xl;

    const int n4x = (int)(NX / 4);
    const int n4w = (int)(NW / 4);
    split_hilo<<<n4x/256, 256, 0, stream>>>(x, Xh, Xl, n4x);
    dim3 gs(n4w/256, 1, 4);
    split4_hilo<<<gs, 256, 0, stream>>>(Wq, Wk, Wv, Wo,
                                        WhQ, WlQ, WhK, WlK, WhV, WlV, WhO, WlO, n4w);

    // QKV: grid x = ROW blocks (32), y = col blocks (8), z = 3
    dim3 gq(MROWS/128, DIMN/128, 3);
    mfma_gemm<4, true><<<gq, 256, 0, stream>>>(Xh, Xl, WhQ, WlQ, WhK, WlK, WhV, WlV,
                                               bq, bk, bv, Qh, Ql, Kh, Kl, Vw, nullptr);

    dim3 gv(SEQ / 64, BATCH * NH);
    convV<<<gv, 256, 0, stream>>>(Vw, Vth, Vtl);

    dim3 ga(16, BATCH * NH);                  // pair-balanced: 68 tiles/block
    attn_mfma<<<ga, 256, 0, stream>>>(Qh, Ql, Kh, Kl, Vth, Vtl, AH, AL);

    // out-proj: BN=64 -> grid (32, 16) = 512 blocks = 2/CU
    dim3 gp(MROWS/128, DIMN/64, 1);
    mfma_gemm<2, false><<<gp, 256, 0, stream>>>(AH, AL, WhO, WlO, nullptr, nullptr,
                                                nullptr, nullptr, bo, nullptr, nullptr,
                                                nullptr, nullptr, nullptr, nullptr,
                                                nullptr, out);
}

// Round 10
// 327.599 us; speedup vs baseline: 1.2587x; 1.0353x over previous
//
#include <hip/hip_runtime.h>
#include <hip/hip_bf16.h>
#include <math.h>

#define DIMN 1024
#define NH 16
#define HD 64
#define BATCH 2
#define SEQ 2048
#define MROWS (BATCH*SEQ)   // 4096

typedef unsigned short u16;
typedef unsigned int u32;
typedef __attribute__((ext_vector_type(8))) short bf16x8;  // 8 bf16 = 4 VGPR
typedef __attribute__((ext_vector_type(4))) float f32x4;

// Q pre-scale folds softmax's log2(e): 1/32 * 1.44269504089
#define QSCALE 0.0450842200279f
// defer-max threshold 8 (nat) -> exp2 domain
#define DEFER_THR 11.5415603372f

__device__ __forceinline__ u16 f2bf(float f) {             // RNE via native cvt
    __hip_bfloat16 h = __float2bfloat16(f);
    return *reinterpret_cast<u16*>(&h);
}
__device__ __forceinline__ float bf2f(u16 s) {
    return __uint_as_float(((unsigned)s) << 16);
}

#define GLOADLDS16(g, s)                                                     \
    __builtin_amdgcn_global_load_lds(                                        \
        (const __attribute__((address_space(1))) void*)(g),                  \
        (__attribute__((address_space(3))) void*)(s), 16, 0, 0)

// ---------------- hi/lo split: fp32 -> bf16 hi + bf16 lo ----------------
// Single launch: z=0 -> x (n4 big), z=1..4 -> weights (n4w each)
__global__ __launch_bounds__(256)
void split5_hilo(const float* __restrict__ s0, const float* __restrict__ s1,
                 const float* __restrict__ s2, const float* __restrict__ s3,
                 const float* __restrict__ s4,
                 u16* __restrict__ h0, u16* __restrict__ l0,
                 u16* __restrict__ h1, u16* __restrict__ l1,
                 u16* __restrict__ h2, u16* __restrict__ l2,
                 u16* __restrict__ h3, u16* __restrict__ l3,
                 u16* __restrict__ h4, u16* __restrict__ l4,
                 int n4x, int n4w)
{
    const float* src; u16* h; u16* l; int n4;
    switch (blockIdx.z) {
        case 0: src = s0; h = h0; l = l0; n4 = n4x; break;
        case 1: src = s1; h = h1; l = l1; n4 = n4w; break;
        case 2: src = s2; h = h2; l = l2; n4 = n4w; break;
        case 3: src = s3; h = h3; l = l3; n4 = n4w; break;
        default: src = s4; h = h4; l = l4; n4 = n4w; break;
    }
    int i = blockIdx.x * 256 + threadIdx.x;
    if (i >= n4) return;
    float4 v = ((const float4*)src)[i];
    ushort4 hv, lv;
    hv.x = f2bf(v.x); lv.x = f2bf(v.x - bf2f(hv.x));
    hv.y = f2bf(v.y); lv.y = f2bf(v.y - bf2f(hv.y));
    hv.z = f2bf(v.z); lv.z = f2bf(v.z - bf2f(hv.z));
    hv.w = f2bf(v.w); lv.w = f2bf(v.w - bf2f(hv.w));
    ((ushort4*)h)[i] = hv;
    ((ushort4*)l)[i] = lv;
}

// ---------------- split-bf16 MFMA GEMM: Y = A @ W^T + bias ----------------
// BM=128 rows, BN = NF*32 cols, BK=32. 4 waves (2x2); wave tile 64 x NF*16.
// blockIdx.x = ROW block (fastest-varying -> same-XCD blocks share W panel).
template<int NF, bool QKV>
__global__ __launch_bounds__(256)
void mfma_gemm(const u16* __restrict__ Ah, const u16* __restrict__ Al,
               const u16* __restrict__ Wh0, const u16* __restrict__ Wl0,
               const u16* __restrict__ Wh1, const u16* __restrict__ Wl1,
               const u16* __restrict__ Wh2, const u16* __restrict__ Wl2,
               const float* __restrict__ b0, const float* __restrict__ b1,
               const float* __restrict__ b2,
               u16* __restrict__ Qh, u16* __restrict__ Ql,
               u16* __restrict__ Kh, u16* __restrict__ Kl,
               float* __restrict__ Vw, float* __restrict__ Yout)
{
    constexpr int BM = 128;
    constexpr int BN = NF * 32;
    constexpr int BK = 32;
    __shared__ u16 AhS[BM*BK], AlS[BM*BK], WhS[BN*BK], WlS[BN*BK];

    const u16* Wh = Wh0; const u16* Wl = Wl0; const float* bias = b0;
    if (QKV) {
        if (blockIdx.z == 1)      { Wh = Wh1; Wl = Wl1; bias = b1; }
        else if (blockIdx.z == 2) { Wh = Wh2; Wl = Wl2; bias = b2; }
    }

    const int tid  = threadIdx.x;
    const int lane = tid & 63;
    const int wid  = tid >> 6;
    const int wr   = wid >> 1;
    const int wc   = wid & 1;

    const int m0 = blockIdx.x * BM;     // row block (x fastest)
    const int n0 = blockIdx.y * BN;

    const int srow = lane >> 2;
    const int skc  = (lane & 3) << 3;
    const int c0 = wid * 2, c1 = wid * 2 + 1;
    const size_t aoffg0 = (size_t)(m0 + c0*16 + srow) * DIMN + skc;
    const size_t aoffg1 = (size_t)(m0 + c1*16 + srow) * DIMN + skc;
    const size_t woffg0 = (size_t)(n0 + c0*16 + srow) * DIMN + skc;
    const size_t woffg1 = (size_t)(n0 + c1*16 + srow) * DIMN + skc;
    const bool doW = (c0 < BN/16);      // NF=2: only waves 0,1 stage W

    f32x4 acc[4][NF];
    #pragma unroll
    for (int m = 0; m < 4; ++m)
        #pragma unroll
        for (int n = 0; n < NF; ++n)
            acc[m][n] = (f32x4){0.f, 0.f, 0.f, 0.f};

    const int fr = lane & 15;
    const int fq = lane >> 4;
    const int aoff = (wr*64 + fr) * BK + fq*8;
    const int boff = (wc*(NF*16) + fr) * BK + fq*8;

    for (int k0 = 0; k0 < DIMN; k0 += BK) {
        GLOADLDS16(Ah + aoffg0 + k0, &AhS[c0*512]);
        GLOADLDS16(Ah + aoffg1 + k0, &AhS[c1*512]);
        GLOADLDS16(Al + aoffg0 + k0, &AlS[c0*512]);
        GLOADLDS16(Al + aoffg1 + k0, &AlS[c1*512]);
        if (doW) {
            GLOADLDS16(Wh + woffg0 + k0, &WhS[c0*512]);
            GLOADLDS16(Wh + woffg1 + k0, &WhS[c1*512]);
            GLOADLDS16(Wl + woffg0 + k0, &WlS[c0*512]);
            GLOADLDS16(Wl + woffg1 + k0, &WlS[c1*512]);
        }
        __syncthreads();

        bf16x8 ah[4], al[4], bh[NF], bl[NF];
        #pragma unroll
        for (int m = 0; m < 4; ++m) {
            ah[m] = *(const bf16x8*)&AhS[aoff + m*16*BK];
            al[m] = *(const bf16x8*)&AlS[aoff + m*16*BK];
        }
        #pragma unroll
        for (int n = 0; n < NF; ++n) {
            bh[n] = *(const bf16x8*)&WhS[boff + n*16*BK];
            bl[n] = *(const bf16x8*)&WlS[boff + n*16*BK];
        }
        #pragma unroll
        for (int m = 0; m < 4; ++m)
            #pragma unroll
            for (int n = 0; n < NF; ++n) {
                acc[m][n] = __builtin_amdgcn_mfma_f32_16x16x32_bf16(ah[m], bh[n], acc[m][n], 0, 0, 0);
                acc[m][n] = __builtin_amdgcn_mfma_f32_16x16x32_bf16(ah[m], bl[n], acc[m][n], 0, 0, 0);
                acc[m][n] = __builtin_amdgcn_mfma_f32_16x16x32_bf16(al[m], bh[n], acc[m][n], 0, 0, 0);
            }
        __syncthreads();
    }

    // C/D map: col = lane&15, row = (lane>>4)*4 + j   [m89-verified]
    #pragma unroll
    for (int n = 0; n < NF; ++n) {
        const int col = n0 + wc*(NF*16) + n*16 + fr;
        const float bv = bias[col];
        #pragma unroll
        for (int m = 0; m < 4; ++m) {
            #pragma unroll
            for (int j = 0; j < 4; ++j) {
                const int row = m0 + wr*64 + m*16 + fq*4 + j;
                float v = acc[m][n][j] + bv;
                if (QKV) {
                    const int b_ = row >> 11, t = row & (SEQ - 1);
                    const int hh = col >> 6, d = col & 63;
                    const size_t rb = (((size_t)b_*NH + hh)*SEQ + t)*HD;
                    if (blockIdx.z == 0) {            // Q: scaled (incl log2e), plain
                        v *= QSCALE;
                        u16 hv = f2bf(v), lv = f2bf(v - bf2f(hv));
                        Qh[rb + d] = hv; Ql[rb + d] = lv;
                    } else if (blockIdx.z == 1) {     // K: d-swizzled for attn LDS
                        u16 hv = f2bf(v), lv = f2bf(v - bf2f(hv));
                        const int ds = d ^ ((t & 7) << 3);
                        Kh[rb + ds] = hv; Kl[rb + ds] = lv;
                    } else {                          // V: fp32 plain
                        Vw[rb + d] = v;
                    }
                } else {
                    Yout[(size_t)row*DIMN + col] = v;
                }
            }
        }
    }
}

// ---- V transpose + hi/lo + kc-slot swizzle: [B,H,T,64] -> [B,H,64,T] bf16 ----
__global__ __launch_bounds__(256)
void convV(const float* __restrict__ Vw, u16* __restrict__ Vth, u16* __restrict__ Vtl)
{
    __shared__ float Vs[64][68];
    const int tid = threadIdx.x;
    const int bh = blockIdx.y;
    const int t0 = blockIdx.x * 64;
    const float* src = Vw + ((size_t)bh*SEQ + t0)*HD;
    #pragma unroll
    for (int k = 0; k < 4; ++k) {
        int f4 = tid + k*256;
        int r = f4 >> 4, c4 = (f4 & 15) << 2;
        *(float4*)&Vs[r][c4] = *(const float4*)(src + (size_t)r*HD + c4);
    }
    __syncthreads();
    const int d  = tid >> 2;            // 0..63
    const int q2 = (tid & 3) << 4;      // base t: 0,16,32,48
    u16* oh = Vth + ((size_t)bh*HD + d)*SEQ + t0;
    u16* ol = Vtl + ((size_t)bh*HD + d)*SEQ + t0;
    #pragma unroll
    for (int p = 0; p < 4; ++p) {
        const int lt = q2 + p*4;                      // linear t, run of 4
        const int t_sw = (lt & 32) | ((((lt >> 3) & 3) ^ (d & 3)) << 3) | (lt & 7);
        ushort4 hv, lv; float v;
        v = Vs[lt + 0][d]; hv.x = f2bf(v); lv.x = f2bf(v - bf2f(hv.x));
        v = Vs[lt + 1][d]; hv.y = f2bf(v); lv.y = f2bf(v - bf2f(hv.y));
        v = Vs[lt + 2][d]; hv.z = f2bf(v); lv.z = f2bf(v - bf2f(hv.z));
        v = Vs[lt + 3][d]; hv.w = f2bf(v); lv.w = f2bf(v - bf2f(hv.w));
        *(ushort4*)(oh + t_sw) = hv;
        *(ushort4*)(ol + t_sw) = lv;
    }
}

// ---------------- MFMA flash attention (pair-balanced, swapped QK^T) --------
// XCD-affinity remap: XCD x (= bid%8 round-robin) owns bh in {4x..4x+3} ->
// per-XCD KV working set 4 MB = L2-resident (was 32 MB -> 255 MB HBM fetch).
// Softmax in exp2 domain (log2e folded into Q scale).
__global__ __launch_bounds__(256)
void attn_mfma(const u16* __restrict__ Qhg, const u16* __restrict__ Qlg,
               const u16* __restrict__ Khg, const u16* __restrict__ Klg,
               const u16* __restrict__ Vthg, const u16* __restrict__ Vtlg,
               u16* __restrict__ AH, u16* __restrict__ AL)
{
    __shared__ u16 KVS[2][4][2048];   // [buf][Kh,Kl,Vth,Vtl][tile] 32 KB
    __shared__ u16 PhS[4][640];       // per-wave P hi [16q][stride 40]
    __shared__ u16 PlS[4][640];

    const int tid  = threadIdx.x;
    const int lane = tid & 63;
    const int w    = tid >> 6;
    const int fr   = lane & 15;
    const int fq   = lane >> 4;

    // XCD-affinity block remap (bijective on 512 blocks)
    const int lin = blockIdx.y * 16 + blockIdx.x;   // 0..511
    const int xcd = lin & 7;
    const int idx = lin >> 3;                       // 0..63
    const int bh  = (xcd << 2) | (idx & 3);         // 0..31
    const int qtp = idx >> 2;                       // 0..15
    const int b_  = bh >> 4;
    const int h   = bh & 15;

    auto stage = [&](int buf, int kt2) {
        u16* dst = &KVS[buf][w][0];
        if (w < 2) {
            const u16* g = (w == 0 ? Khg : Klg) +
                ((size_t)bh*SEQ + (size_t)kt2*32 + (lane>>3))*HD + ((lane&7)<<3);
            #pragma unroll
            for (int i = 0; i < 4; ++i)
                GLOADLDS16(g + (size_t)i*8*HD, dst + i*512);
        } else {
            const u16* g = (w == 2 ? Vthg : Vtlg) +
                ((size_t)bh*HD + (lane>>2))*SEQ + (size_t)kt2*32 + ((lane&3)<<3);
            #pragma unroll
            for (int i = 0; i < 4; ++i)
                GLOADLDS16(g + (size_t)i*16*SEQ, dst + i*512);
        }
    };

    #pragma unroll 1
    for (int pass = 0; pass < 2; ++pass) {
        const int qt   = pass ? (31 - qtp) : qtp;
        const int qabs = qt*64 + w*16 + fr;
        const int nt   = 2*qt + 2;

        bf16x8 qh[2], ql[2];
        {
            const size_t qrow = ((size_t)bh*SEQ + qabs)*HD;
            #pragma unroll
            for (int ks = 0; ks < 2; ++ks) {
                qh[ks] = *(const bf16x8*)&Qhg[qrow + ks*32 + (fq<<3)];
                ql[ks] = *(const bf16x8*)&Qlg[qrow + ks*32 + (fq<<3)];
            }
        }

        f32x4 o[4];
        #pragma unroll
        for (int md = 0; md < 4; ++md) o[md] = (f32x4){0.f,0.f,0.f,0.f};
        float mrun = -INFINITY, lrun = 0.f;

        __syncthreads();               // prior pass's LDS reads complete
        stage(0, 0);
        int cur = 0;

        for (int kt = 0; kt < nt; ++kt) {
            __syncthreads();                       // staged tile landed
            if (kt + 1 < nt) stage(cur ^ 1, kt + 1);

            f32x4 s0 = (f32x4){0.f,0.f,0.f,0.f};
            f32x4 s1 = (f32x4){0.f,0.f,0.f,0.f};
            __builtin_amdgcn_s_setprio(1);
            #pragma unroll
            for (int ks = 0; ks < 2; ++ks) {
                const int sl = (((ks*4 + fq) ^ (fr & 7)) << 3);   // swizzled d-slot
                bf16x8 a0h = *(const bf16x8*)&KVS[cur][0][fr*64 + sl];
                bf16x8 a0l = *(const bf16x8*)&KVS[cur][1][fr*64 + sl];
                bf16x8 a1h = *(const bf16x8*)&KVS[cur][0][(16+fr)*64 + sl];
                bf16x8 a1l = *(const bf16x8*)&KVS[cur][1][(16+fr)*64 + sl];
                s0 = __builtin_amdgcn_mfma_f32_16x16x32_bf16(a0h, qh[ks], s0, 0,0,0);
                s0 = __builtin_amdgcn_mfma_f32_16x16x32_bf16(a0h, ql[ks], s0, 0,0,0);
                s0 = __builtin_amdgcn_mfma_f32_16x16x32_bf16(a0l, qh[ks], s0, 0,0,0);
                s1 = __builtin_amdgcn_mfma_f32_16x16x32_bf16(a1h, qh[ks], s1, 0,0,0);
                s1 = __builtin_amdgcn_mfma_f32_16x16x32_bf16(a1h, ql[ks], s1, 0,0,0);
                s1 = __builtin_amdgcn_mfma_f32_16x16x32_bf16(a1l, qh[ks], s1, 0,0,0);
            }
            __builtin_amdgcn_s_setprio(0);

            const int kb = kt*32 + fq*4;
            #pragma unroll
            for (int j = 0; j < 4; ++j) {
                if (kb + j      > qabs) s0[j] = -INFINITY;
                if (kb + 16 + j > qabs) s1[j] = -INFINITY;
            }

            float pm = fmaxf(fmaxf(fmaxf(s0[0],s0[1]), fmaxf(s0[2],s0[3])),
                             fmaxf(fmaxf(s1[0],s1[1]), fmaxf(s1[2],s1[3])));
            pm = fmaxf(pm, __shfl_xor(pm, 16));
            pm = fmaxf(pm, __shfl_xor(pm, 32));

            // T13 defer-max (exp2 domain): rescale only when growth > 8 nats.
            if (!__all(pm - mrun <= DEFER_THR)) {
                const float mnew = fmaxf(mrun, pm);
                const float fac  = exp2f(mrun - mnew);
                lrun *= fac;
                #pragma unroll
                for (int md = 0; md < 4; ++md) {
                    o[md][0] *= fac; o[md][1] *= fac;
                    o[md][2] *= fac; o[md][3] *= fac;
                }
                mrun = mnew;
            }
            float p[8];
            #pragma unroll
            for (int j = 0; j < 4; ++j) {
                p[j]   = exp2f(s0[j] - mrun);
                p[4+j] = exp2f(s1[j] - mrun);
            }
            float ls = ((p[0]+p[1]) + (p[2]+p[3])) + ((p[4]+p[5]) + (p[6]+p[7]));
            ls += __shfl_xor(ls, 16);
            ls += __shfl_xor(ls, 32);
            lrun += ls;

            u16 ph[8], pl[8];
            #pragma unroll
            for (int i = 0; i < 8; ++i) {
                ph[i] = f2bf(p[i]);
                pl[i] = f2bf(p[i] - bf2f(ph[i]));
            }
            {
                const int pb = fr*40 + fq*4;
                uint2 w0, w1;
                w0.x = (u32)ph[0] | ((u32)ph[1] << 16);
                w0.y = (u32)ph[2] | ((u32)ph[3] << 16);
                w1.x = (u32)ph[4] | ((u32)ph[5] << 16);
                w1.y = (u32)ph[6] | ((u32)ph[7] << 16);
                *(uint2*)&PhS[w][pb]      = w0;
                *(uint2*)&PhS[w][pb + 16] = w1;
                w0.x = (u32)pl[0] | ((u32)pl[1] << 16);
                w0.y = (u32)pl[2] | ((u32)pl[3] << 16);
                w1.x = (u32)pl[4] | ((u32)pl[5] << 16);
                w1.y = (u32)pl[6] | ((u32)pl[7] << 16);
                *(uint2*)&PlS[w][pb]      = w0;
                *(uint2*)&PlS[w][pb + 16] = w1;
            }

            bf16x8 bph = *(const bf16x8*)&PhS[w][fr*40 + (fq<<3)];
            bf16x8 bpl = *(const bf16x8*)&PlS[w][fr*40 + (fq<<3)];
            __builtin_amdgcn_s_setprio(1);
            #pragma unroll
            for (int md = 0; md < 4; ++md) {
                const int vsl = ((fq ^ (fr & 3)) << 3);
                bf16x8 avh = *(const bf16x8*)&KVS[cur][2][(md*16+fr)*32 + vsl];
                bf16x8 avl = *(const bf16x8*)&KVS[cur][3][(md*16+fr)*32 + vsl];
                o[md] = __builtin_amdgcn_mfma_f32_16x16x32_bf16(avh, bph, o[md], 0,0,0);
                o[md] = __builtin_amdgcn_mfma_f32_16x16x32_bf16(avh, bpl, o[md], 0,0,0);
                o[md] = __builtin_amdgcn_mfma_f32_16x16x32_bf16(avl, bph, o[md], 0,0,0);
            }
            __builtin_amdgcn_s_setprio(0);
            cur ^= 1;
        }

        // epilogue: hi/lo context in natural [B,T,DIMN] layout for the proj
        const float inv = 1.f / lrun;
        const size_t ob = ((size_t)b_*SEQ + qabs)*DIMN + h*64;
        #pragma unroll
        for (int md = 0; md < 4; ++md) {
            #pragma unroll
            for (int pr = 0; pr < 2; ++pr) {
                const int d0 = md*16 + fq*4 + pr*2;
                const float v0 = o[md][pr*2]   * inv;
                const float v1 = o[md][pr*2+1] * inv;
                u16 h0 = f2bf(v0), l0 = f2bf(v0 - bf2f(h0));
                u16 h1 = f2bf(v1), l1 = f2bf(v1 - bf2f(h1));
                *(u32*)&AH[ob + d0] = (u32)h0 | ((u32)h1 << 16);
                *(u32*)&AL[ob + d0] = (u32)l0 | ((u32)l1 << 16);
            }
        }
    }
}

extern "C" void kernel_launch(void* const* d_in, const int* in_sizes, int n_in,
                              void* d_out, int out_size, void* d_ws, size_t ws_size,
                              hipStream_t stream)
{
    const float* x  = (const float*)d_in[0];
    const float* Wq = (const float*)d_in[1];
    const float* bq = (const float*)d_in[2];
    const float* Wk = (const float*)d_in[3];
    const float* bk = (const float*)d_in[4];
    const float* Wv = (const float*)d_in[5];
    const float* bv = (const float*)d_in[6];
    const float* Wo = (const float*)d_in[7];
    const float* bo = (const float*)d_in[8];
    float* out = (float*)d_out;

    const size_t NX = (size_t)MROWS * DIMN;   // 4 Mi elems
    const size_t NW = (size_t)DIMN * DIMN;    // 1 Mi elems

    // 96 MB workspace
    u16* Xh  = (u16*)d_ws;
    u16* Xl  = Xh  + NX;
    u16* WhQ = Xl  + NX;  u16* WlQ = WhQ + NW;
    u16* WhK = WlQ + NW;  u16* WlK = WhK + NW;
    u16* WhV = WlK + NW;  u16* WlV = WhV + NW;
    u16* WhO = WlV + NW;  u16* WlO = WhO + NW;
    u16* Qh  = WlO + NW;
    u16* Ql  = Qh + NX;
    u16* Kh  = Ql + NX;
    u16* Kl  = Kh + NX;
    u16* Vth = Kl + NX;
    u16* Vtl = Vth + NX;
    float* Vw = (float*)(Vtl + NX);           // NX fp32
    u16* AH = Xh;                              // reuse (x-split dead after QKV)
    u16* AL = Xl;

    const int n4x = (int)(NX / 4);
    const int n4w = (int)(NW / 4);
    dim3 gs(n4x/256, 1, 5);                   // z=0: x; z=1..4: weights (early-exit tail)
    split5_hilo<<<gs, 256, 0, stream>>>(x, Wq, Wk, Wv, Wo,
                                        Xh, Xl, WhQ, WlQ, WhK, WlK, WhV, WlV,
                                        WhO, WlO, n4x, n4w);

    // QKV: grid x = ROW blocks (32), y = col blocks (8), z = 3
    dim3 gq(MROWS/128, DIMN/128, 3);
    mfma_gemm<4, true><<<gq, 256, 0, stream>>>(Xh, Xl, WhQ, WlQ, WhK, WlK, WhV, WlV,
                                               bq, bk, bv, Qh, Ql, Kh, Kl, Vw, nullptr);

    dim3 gv(SEQ / 64, BATCH * NH);
    convV<<<gv, 256, 0, stream>>>(Vw, Vth, Vtl);

    dim3 ga(16, BATCH * NH);                  // pair-balanced + XCD-affinity
    attn_mfma<<<ga, 256, 0, stream>>>(Qh, Ql, Kh, Kl, Vth, Vtl, AH, AL);

    // out-proj: BN=64 -> grid (32, 16) = 512 blocks = 2/CU
    dim3 gp(MROWS/128, DIMN/64, 1);
    mfma_gemm<2, false><<<gp, 256, 0, stream>>>(AH, AL, WhO, WlO, nullptr, nullptr,
                                                nullptr, nullptr, bo, nullptr, nullptr,
                                                nullptr, nullptr, nullptr, nullptr,
                                                nullptr, out);
}